// Round 6
// baseline (418.486 us; speedup 1.0000x reference)
//
#include <hip/hip_runtime.h>
#include <hip/hip_bf16.h>

#define DIM 128

// ======================= CSR build =======================

__global__ void edge_count(int* __restrict__ deg, const int* __restrict__ dst, int E) {
    int e = blockIdx.x * blockDim.x + threadIdx.x;
    if (e < E) atomicAdd(&deg[dst[e]], 1);
}

// Bucket starts padded to multiples of 4 (pad slots are zero-filled by a
// prior memset: nrm=0 -> contribute 0). Per-wave scan + one cursor atomic.
__global__ __launch_bounds__(256) void alloc_offsets(
    const int* __restrict__ deg, int* __restrict__ start, int* __restrict__ end_,
    int* __restrict__ cursor, float* __restrict__ dinv, int* total, int N)
{
    int i = blockIdx.x * blockDim.x + threadIdx.x;
    int lane = threadIdx.x & 63;
    int d  = (i < N) ? deg[i] : 0;
    int d4 = (d + 3) & ~3;
    int pre = d4;
    #pragma unroll
    for (int off = 1; off < 64; off <<= 1) {
        int v = __shfl_up(pre, off, 64);
        if (lane >= off) pre += v;
    }
    int waveTot = __shfl(pre, 63, 64);
    int base = 0;
    if (lane == 63) base = atomicAdd(total, waveTot);
    base = __shfl(base, 63, 64);
    if (i < N) {
        int st = base + pre - d4;
        start[i]  = st;
        end_[i]   = st + d;
        cursor[i] = st;
        dinv[i]   = rsqrtf((float)(d + 1));   // +1 self-loop
    }
}

__global__ void scatter_edges(const int* __restrict__ src, const int* __restrict__ dst,
                              const float* __restrict__ dinv, int* __restrict__ cursor,
                              int* __restrict__ csr_src, float* __restrict__ csr_nrm, int E)
{
    int e = blockIdx.x * blockDim.x + threadIdx.x;
    if (e >= E) return;
    int s = src[e], d = dst[e];
    int p = atomicAdd(&cursor[d], 1);
    csr_src[p] = s;
    csr_nrm[p] = dinv[s] * dinv[d];
}

// ======================= gather aggregation =======================
// One wave per dst node: acc = dinv^2*H[node] + sum nrm*H[src], float2/lane.
// Bucket length is a multiple of 4: main loop takes 8 edges (int4/float4
// metadata + 8 independent row loads in flight), remainder is one 4-chunk.
template<int FUSE_POOL>
__global__ __launch_bounds__(256) void gather_agg(
    const float* __restrict__ H, float* __restrict__ O,
    const int* __restrict__ csr_src, const float* __restrict__ csr_nrm,
    const int* __restrict__ start, const int* __restrict__ end_,
    const float* __restrict__ dinv, int N,
    const float* __restrict__ b2, const float* __restrict__ wlin,
    const int* __restrict__ batch, float* __restrict__ sums, float* __restrict__ cnt)
{
    int wave = threadIdx.x >> 6;
    int lane = threadIdx.x & 63;
    int node = blockIdx.x * 4 + wave;
    if (node >= N) return;

    int st = start[node], en = end_[node];
    int en_pad = st + ((en - st + 3) & ~3);
    const float* Hl = H + lane * 2;

    float di = dinv[node];
    float nn = di * di;
    float2 acc;
    {
        float2 hv = *(const float2*)&Hl[(size_t)node * DIM];
        acc.x = hv.x * nn;
        acc.y = hv.y * nn;
    }

    int j = st;
    for (; j + 8 <= en_pad; j += 8) {
        int4   sa = *(const int4*)  &csr_src[j];
        int4   sb = *(const int4*)  &csr_src[j + 4];
        float4 na = *(const float4*)&csr_nrm[j];
        float4 nb = *(const float4*)&csr_nrm[j + 4];
        float2 h0 = *(const float2*)&Hl[(size_t)sa.x * DIM];
        float2 h1 = *(const float2*)&Hl[(size_t)sa.y * DIM];
        float2 h2 = *(const float2*)&Hl[(size_t)sa.z * DIM];
        float2 h3 = *(const float2*)&Hl[(size_t)sa.w * DIM];
        float2 h4 = *(const float2*)&Hl[(size_t)sb.x * DIM];
        float2 h5 = *(const float2*)&Hl[(size_t)sb.y * DIM];
        float2 h6 = *(const float2*)&Hl[(size_t)sb.z * DIM];
        float2 h7 = *(const float2*)&Hl[(size_t)sb.w * DIM];
        acc.x = fmaf(h0.x, na.x, acc.x);  acc.y = fmaf(h0.y, na.x, acc.y);
        acc.x = fmaf(h1.x, na.y, acc.x);  acc.y = fmaf(h1.y, na.y, acc.y);
        acc.x = fmaf(h2.x, na.z, acc.x);  acc.y = fmaf(h2.y, na.z, acc.y);
        acc.x = fmaf(h3.x, na.w, acc.x);  acc.y = fmaf(h3.y, na.w, acc.y);
        acc.x = fmaf(h4.x, nb.x, acc.x);  acc.y = fmaf(h4.y, nb.x, acc.y);
        acc.x = fmaf(h5.x, nb.y, acc.x);  acc.y = fmaf(h5.y, nb.y, acc.y);
        acc.x = fmaf(h6.x, nb.z, acc.x);  acc.y = fmaf(h6.y, nb.z, acc.y);
        acc.x = fmaf(h7.x, nb.w, acc.x);  acc.y = fmaf(h7.y, nb.w, acc.y);
    }
    if (j < en_pad) {   // exactly one 4-chunk
        int4   sa = *(const int4*)  &csr_src[j];
        float4 na = *(const float4*)&csr_nrm[j];
        float2 h0 = *(const float2*)&Hl[(size_t)sa.x * DIM];
        float2 h1 = *(const float2*)&Hl[(size_t)sa.y * DIM];
        float2 h2 = *(const float2*)&Hl[(size_t)sa.z * DIM];
        float2 h3 = *(const float2*)&Hl[(size_t)sa.w * DIM];
        acc.x = fmaf(h0.x, na.x, acc.x);  acc.y = fmaf(h0.y, na.x, acc.y);
        acc.x = fmaf(h1.x, na.y, acc.x);  acc.y = fmaf(h1.y, na.y, acc.y);
        acc.x = fmaf(h2.x, na.z, acc.x);  acc.y = fmaf(h2.y, na.z, acc.y);
        acc.x = fmaf(h3.x, na.w, acc.x);  acc.y = fmaf(h3.y, na.w, acc.y);
    }

    if (FUSE_POOL) {
        float v = fmaxf(acc.x + b2[lane * 2], 0.f)     * wlin[lane * 2]
                + fmaxf(acc.y + b2[lane * 2 + 1], 0.f) * wlin[lane * 2 + 1];
        #pragma unroll
        for (int m = 32; m >= 1; m >>= 1) v += __shfl_xor(v, m, 64);
        if (lane == 0) {
            int g = batch[node];
            unsafeAtomicAdd(&sums[g], v);
            unsafeAtomicAdd(&cnt[g], 1.0f);
        }
    } else {
        *(float2*)&O[(size_t)node * DIM + lane * 2] = acc;
    }
}

// ======================= GEMM =======================
// BM=64 x BN=128 x BK=32 LDS-tiled outer product; 256 threads;
// thread tile 8 nodes x 4 features. MODE 1 fuses relu(x+bias) on input.

template<int MODE>
__global__ __launch_bounds__(256) void gemm_nodes(
    const float* __restrict__ X,
    const float* __restrict__ bias,
    const float* __restrict__ W,   // [128][128] row-major (k, f)
    float* __restrict__ Y, int N)
{
    __shared__ float As[32][72];
    __shared__ float Bs[32][132];
    const int t = threadIdx.x;
    const int node0 = blockIdx.x * 64;
    const int tx = t & 31;
    const int ty = t >> 5;
    const int f0 = tx * 4;
    const int n0 = ty * 8;

    float acc[8][4];
    #pragma unroll
    for (int i = 0; i < 8; ++i)
        #pragma unroll
        for (int j = 0; j < 4; ++j) acc[i][j] = 0.f;

    const int sr  = t >> 3;
    const int sc4 = (t & 7) * 4;

    for (int k0 = 0; k0 < DIM; k0 += 32) {
        #pragma unroll
        for (int half = 0; half < 2; ++half) {
            int r = sr + half * 32;
            int node = node0 + r;
            float v[4] = {0.f, 0.f, 0.f, 0.f};
            if (node < N)
                *(float4*)v = *(const float4*)&X[(size_t)node * DIM + k0 + sc4];
            if (MODE == 1) {
                float bv[4];
                *(float4*)bv = *(const float4*)&bias[k0 + sc4];
                #pragma unroll
                for (int i = 0; i < 4; ++i) v[i] = fmaxf(v[i] + bv[i], 0.f);
                if (node >= N) { v[0]=v[1]=v[2]=v[3]=0.f; }
            }
            #pragma unroll
            for (int i = 0; i < 4; ++i) As[sc4 + i][r] = v[i];
        }
        #pragma unroll
        for (int i = 0; i < 4; ++i) {
            int kk = (t >> 5) + i * 8;
            float4 wv = *(const float4*)&W[(size_t)(k0 + kk) * DIM + f0];
            *(float4*)&Bs[kk][f0] = wv;
        }
        __syncthreads();

        #pragma unroll 4
        for (int kk = 0; kk < 32; ++kk) {
            float4 a0 = *(const float4*)&As[kk][n0];
            float4 a1 = *(const float4*)&As[kk][n0 + 4];
            float4 b  = *(const float4*)&Bs[kk][f0];
            float av[8] = {a0.x,a0.y,a0.z,a0.w,a1.x,a1.y,a1.z,a1.w};
            float bv[4] = {b.x,b.y,b.z,b.w};
            #pragma unroll
            for (int i = 0; i < 8; ++i)
                #pragma unroll
                for (int j = 0; j < 4; ++j)
                    acc[i][j] = fmaf(av[i], bv[j], acc[i][j]);
        }
        __syncthreads();
    }

    #pragma unroll
    for (int i = 0; i < 8; ++i) {
        int node = node0 + n0 + i;
        if (node < N)
            *(float4*)&Y[(size_t)node * DIM + f0] =
                make_float4(acc[i][0], acc[i][1], acc[i][2], acc[i][3]);
    }
}

__global__ void final_kernel(const float* __restrict__ sums,
                             const float* __restrict__ cnt,
                             const float* __restrict__ blin,
                             float* __restrict__ out, int G)
{
    int g = blockIdx.x * blockDim.x + threadIdx.x;
    if (g < G) out[g] = sums[g] / fmaxf(cnt[g], 1.0f) + blin[0];
}

// ======================= fallback (atomic) path =======================

__global__ void deg_init(float* deg, int n) {
    int i = blockIdx.x * blockDim.x + threadIdx.x;
    if (i < n) deg[i] = 1.0f;
}
__global__ void edge_deg(float* deg, const int* __restrict__ dst, int E) {
    int e = blockIdx.x * blockDim.x + threadIdx.x;
    if (e < E) unsafeAtomicAdd(&deg[dst[e]], 1.0f);
}
__global__ void deg_fin(float* deg, int n) {
    int i = blockIdx.x * blockDim.x + threadIdx.x;
    if (i < n) deg[i] = rsqrtf(deg[i]);
}
__global__ void self_loop(const float* __restrict__ H, float* __restrict__ O,
                          const float* __restrict__ dinv, int N)
{
    size_t tid = (size_t)blockIdx.x * blockDim.x + threadIdx.x;
    int i = (int)(tid >> 5);
    if (i >= N) return;
    int f = ((int)tid & 31) * 4;
    float di = dinv[i]; float nrm = di * di;
    float4 hv = *(const float4*)&H[(size_t)i * DIM + f];
    *(float4*)&O[(size_t)i * DIM + f] =
        make_float4(hv.x*nrm, hv.y*nrm, hv.z*nrm, hv.w*nrm);
}
__global__ void edge_agg(const float* __restrict__ H, float* __restrict__ O,
                         const int* __restrict__ src, const int* __restrict__ dst,
                         const float* __restrict__ dinv, int E)
{
    size_t tid = (size_t)blockIdx.x * blockDim.x + threadIdx.x;
    int e = (int)(tid >> 5);
    if (e >= E) return;
    int f = ((int)tid & 31) * 4;
    int s = src[e], d = dst[e];
    float norm = dinv[s] * dinv[d];
    float4 hv = *(const float4*)&H[(size_t)s * DIM + f];
    float* o = &O[(size_t)d * DIM + f];
    unsafeAtomicAdd(o + 0, hv.x * norm);
    unsafeAtomicAdd(o + 1, hv.y * norm);
    unsafeAtomicAdd(o + 2, hv.z * norm);
    unsafeAtomicAdd(o + 3, hv.w * norm);
}
__global__ __launch_bounds__(256) void pool_kernel(
    const float* __restrict__ H, const float* __restrict__ b2,
    const float* __restrict__ wlin, const int* __restrict__ batch,
    float* __restrict__ sums, float* __restrict__ cnt, int N)
{
    int wave = threadIdx.x >> 6;
    int lane = threadIdx.x & 63;
    int node = blockIdx.x * 4 + wave;
    if (node >= N) return;
    float v = fmaxf(H[(size_t)node*DIM + lane] + b2[lane], 0.f) * wlin[lane]
            + fmaxf(H[(size_t)node*DIM + 64 + lane] + b2[64+lane], 0.f) * wlin[64+lane];
    #pragma unroll
    for (int m = 32; m >= 1; m >>= 1) v += __shfl_xor(v, m, 64);
    if (lane == 0) {
        int g = batch[node];
        unsafeAtomicAdd(&sums[g], v);
        unsafeAtomicAdd(&cnt[g], 1.0f);
    }
}

// ======================= launch =======================

extern "C" void kernel_launch(void* const* d_in, const int* in_sizes, int n_in,
                              void* d_out, int out_size, void* d_ws, size_t ws_size,
                              hipStream_t stream)
{
    const float* x    = (const float*)d_in[0];
    const int*   src  = (const int*)d_in[1];
    const int*   dst  = (const int*)d_in[2];
    const int*   batch= (const int*)d_in[3];
    const float* W1   = (const float*)d_in[5];
    const float* b1   = (const float*)d_in[6];
    const float* W2   = (const float*)d_in[7];
    const float* b2   = (const float*)d_in[8];
    const float* wlin = (const float*)d_in[9];
    const float* blin = (const float*)d_in[10];
    float* out = (float*)d_out;

    const int N = in_sizes[0] / DIM;
    const int E = in_sizes[1];
    const int G = out_size;
    const size_t E_pad = (size_t)E + 4 * (size_t)N;   // per-bucket pad to x4

    float* ws = (float*)d_ws;
    size_t nf = (size_t)N * DIM;

    float* B0    = ws;
    float* B1    = B0 + nf;
    float* dinv  = B1 + nf;
    float* sums  = dinv + N;
    float* cnt   = sums + G;
    int*   deg_c = (int*)(cnt + G);
    int*   start = deg_c + N;
    int*   end_  = start + N;
    int*   csrs  = end_ + N;
    float* csrn  = (float*)(csrs + E_pad);
    int*   total = (int*)(csrn + E_pad);
    size_t need_bytes = ((size_t)(total + 1) - (size_t)ws);

    const int gblocks = (N + 63) / 64;
    const int eblocks = (E + 255) / 256;

    if (ws_size >= need_bytes) {
        // ---- CSR build (once, reused by both layers) ----
        hipMemsetAsync(deg_c, 0, sizeof(int) * (size_t)N, stream);
        hipMemsetAsync(total, 0, sizeof(int), stream);
        hipMemsetAsync(sums, 0, sizeof(float) * 2 * (size_t)G, stream);
        hipMemsetAsync(csrs, 0, sizeof(int) * 2 * E_pad, stream);  // zero pad slots
        edge_count<<<eblocks, 256, 0, stream>>>(deg_c, dst, E);
        alloc_offsets<<<(N + 255) / 256, 256, 0, stream>>>(deg_c, start, end_, deg_c,
                                                           dinv, total, N);
        scatter_edges<<<eblocks, 256, 0, stream>>>(src, dst, dinv, deg_c, csrs, csrn, E);

        // ---- layer 1 ----
        gemm_nodes<0><<<gblocks, 256, 0, stream>>>(x, nullptr, W1, B0, N);
        gather_agg<0><<<(N + 3) / 4, 256, 0, stream>>>(B0, B1, csrs, csrn, start, end_,
                                                       dinv, N, nullptr, nullptr,
                                                       nullptr, nullptr, nullptr);
        // ---- layer 2 (gather fused with pooling) ----
        gemm_nodes<1><<<gblocks, 256, 0, stream>>>(B1, b1, W2, B0, N);
        gather_agg<1><<<(N + 3) / 4, 256, 0, stream>>>(B0, nullptr, csrs, csrn, start,
                                                       end_, dinv, N, b2, wlin,
                                                       batch, sums, cnt);
        final_kernel<<<(G + 255) / 256, 256, 0, stream>>>(sums, cnt, blin, out, G);
    } else {
        // ---- fallback: atomic scatter path ----
        const int nthr32 = N * 32;
        const long long ethr = (long long)E * 32;
        deg_init<<<(N + 255) / 256, 256, 0, stream>>>(dinv, N);
        edge_deg<<<eblocks, 256, 0, stream>>>(dinv, dst, E);
        deg_fin <<<(N + 255) / 256, 256, 0, stream>>>(dinv, N);
        gemm_nodes<0><<<gblocks, 256, 0, stream>>>(x, nullptr, W1, B0, N);
        self_loop<<<(nthr32 + 255) / 256, 256, 0, stream>>>(B0, B1, dinv, N);
        edge_agg<<<(int)((ethr + 255) / 256), 256, 0, stream>>>(B0, B1, src, dst, dinv, E);
        gemm_nodes<1><<<gblocks, 256, 0, stream>>>(B1, b1, W2, B0, N);
        self_loop<<<(nthr32 + 255) / 256, 256, 0, stream>>>(B0, B1, dinv, N);
        edge_agg<<<(int)((ethr + 255) / 256), 256, 0, stream>>>(B0, B1, src, dst, dinv, E);
        hipMemsetAsync(sums, 0, sizeof(float) * 2 * (size_t)G, stream);
        pool_kernel<<<(N + 3) / 4, 256, 0, stream>>>(B1, b2, wlin, batch, sums, cnt, N);
        final_kernel<<<(G + 255) / 256, 256, 0, stream>>>(sums, cnt, blin, out, G);
    }
}

// Round 7
// 389.557 us; speedup vs baseline: 1.0743x; 1.0743x over previous
//
#include <hip/hip_runtime.h>
#include <hip/hip_bf16.h>

#define DIM 128
typedef unsigned int u32;

// bf16x2 pack/unpack: low ushort = even feature, high = odd feature.
__device__ __forceinline__ u32 pack_bf16x2(float a, float b) {
    u32 ua = __float_as_uint(a), ub = __float_as_uint(b);
    ua = (ua + 0x7FFFu + ((ua >> 16) & 1u)) >> 16;        // RNE
    ub = (ub + 0x7FFFu + ((ub >> 16) & 1u)) >> 16;
    return ua | (ub << 16);
}
__device__ __forceinline__ float2 unpack_bf16x2(u32 h) {
    return make_float2(__uint_as_float(h << 16), __uint_as_float(h & 0xFFFF0000u));
}

// ======================= CSR build =======================

__global__ void edge_count(int* __restrict__ deg, const int* __restrict__ dst, int E) {
    int e = blockIdx.x * blockDim.x + threadIdx.x;
    if (e < E) atomicAdd(&deg[dst[e]], 1);
}

// Bucket starts padded to multiples of 4 (pad slots zero-filled: nrm=0).
__global__ __launch_bounds__(256) void alloc_offsets(
    const int* __restrict__ deg, int* __restrict__ start, int* __restrict__ end_,
    int* __restrict__ cursor, float* __restrict__ dinv, int* total, int N)
{
    int i = blockIdx.x * blockDim.x + threadIdx.x;
    int lane = threadIdx.x & 63;
    int d  = (i < N) ? deg[i] : 0;
    int d4 = (d + 3) & ~3;
    int pre = d4;
    #pragma unroll
    for (int off = 1; off < 64; off <<= 1) {
        int v = __shfl_up(pre, off, 64);
        if (lane >= off) pre += v;
    }
    int waveTot = __shfl(pre, 63, 64);
    int base = 0;
    if (lane == 63) base = atomicAdd(total, waveTot);
    base = __shfl(base, 63, 64);
    if (i < N) {
        int st = base + pre - d4;
        start[i]  = st;
        end_[i]   = st + d;
        cursor[i] = st;
        dinv[i]   = rsqrtf((float)(d + 1));   // +1 self-loop
    }
}

__global__ void scatter_edges(const int* __restrict__ src, const int* __restrict__ dst,
                              const float* __restrict__ dinv, int* __restrict__ cursor,
                              int* __restrict__ csr_src, float* __restrict__ csr_nrm, int E)
{
    int e = blockIdx.x * blockDim.x + threadIdx.x;
    if (e >= E) return;
    int s = src[e], d = dst[e];
    int p = atomicAdd(&cursor[d], 1);
    csr_src[p] = s;
    csr_nrm[p] = dinv[s] * dinv[d];
}

// ======================= gather aggregation (bf16 rows) =======================
// One wave per dst node; lane handles features {2l, 2l+1} via one dword.
// Row = 256 B (2 L2 lines). fp32 accumulate. Bucket length multiple of 4.
template<int FUSE_POOL>
__global__ __launch_bounds__(256) void gather_agg(
    const u32* __restrict__ H, u32* __restrict__ O,
    const int* __restrict__ csr_src, const float* __restrict__ csr_nrm,
    const int* __restrict__ start, const int* __restrict__ end_,
    const float* __restrict__ dinv, int N,
    const float* __restrict__ b2, const float* __restrict__ wlin,
    const int* __restrict__ batch, float* __restrict__ sums, float* __restrict__ cnt)
{
    int wave = threadIdx.x >> 6;
    int lane = threadIdx.x & 63;
    int node = blockIdx.x * 4 + wave;
    if (node >= N) return;

    int st = start[node], en = end_[node];
    int en_pad = st + ((en - st + 3) & ~3);
    const u32* Hl = H + lane;          // row stride 64 dwords

    float di = dinv[node];
    float nn = di * di;
    float2 acc;
    {
        float2 hv = unpack_bf16x2(Hl[(size_t)node * 64]);
        acc.x = hv.x * nn;
        acc.y = hv.y * nn;
    }

    int j = st;
    for (; j + 8 <= en_pad; j += 8) {
        int4   sa = *(const int4*)  &csr_src[j];
        int4   sb = *(const int4*)  &csr_src[j + 4];
        float4 na = *(const float4*)&csr_nrm[j];
        float4 nb = *(const float4*)&csr_nrm[j + 4];
        u32 r0 = Hl[(size_t)sa.x * 64];
        u32 r1 = Hl[(size_t)sa.y * 64];
        u32 r2 = Hl[(size_t)sa.z * 64];
        u32 r3 = Hl[(size_t)sa.w * 64];
        u32 r4 = Hl[(size_t)sb.x * 64];
        u32 r5 = Hl[(size_t)sb.y * 64];
        u32 r6 = Hl[(size_t)sb.z * 64];
        u32 r7 = Hl[(size_t)sb.w * 64];
        float2 h0 = unpack_bf16x2(r0), h1 = unpack_bf16x2(r1);
        float2 h2 = unpack_bf16x2(r2), h3 = unpack_bf16x2(r3);
        float2 h4 = unpack_bf16x2(r4), h5 = unpack_bf16x2(r5);
        float2 h6 = unpack_bf16x2(r6), h7 = unpack_bf16x2(r7);
        acc.x = fmaf(h0.x, na.x, acc.x);  acc.y = fmaf(h0.y, na.x, acc.y);
        acc.x = fmaf(h1.x, na.y, acc.x);  acc.y = fmaf(h1.y, na.y, acc.y);
        acc.x = fmaf(h2.x, na.z, acc.x);  acc.y = fmaf(h2.y, na.z, acc.y);
        acc.x = fmaf(h3.x, na.w, acc.x);  acc.y = fmaf(h3.y, na.w, acc.y);
        acc.x = fmaf(h4.x, nb.x, acc.x);  acc.y = fmaf(h4.y, nb.x, acc.y);
        acc.x = fmaf(h5.x, nb.y, acc.x);  acc.y = fmaf(h5.y, nb.y, acc.y);
        acc.x = fmaf(h6.x, nb.z, acc.x);  acc.y = fmaf(h6.y, nb.z, acc.y);
        acc.x = fmaf(h7.x, nb.w, acc.x);  acc.y = fmaf(h7.y, nb.w, acc.y);
    }
    if (j < en_pad) {   // exactly one 4-chunk
        int4   sa = *(const int4*)  &csr_src[j];
        float4 na = *(const float4*)&csr_nrm[j];
        u32 r0 = Hl[(size_t)sa.x * 64];
        u32 r1 = Hl[(size_t)sa.y * 64];
        u32 r2 = Hl[(size_t)sa.z * 64];
        u32 r3 = Hl[(size_t)sa.w * 64];
        float2 h0 = unpack_bf16x2(r0), h1 = unpack_bf16x2(r1);
        float2 h2 = unpack_bf16x2(r2), h3 = unpack_bf16x2(r3);
        acc.x = fmaf(h0.x, na.x, acc.x);  acc.y = fmaf(h0.y, na.x, acc.y);
        acc.x = fmaf(h1.x, na.y, acc.x);  acc.y = fmaf(h1.y, na.y, acc.y);
        acc.x = fmaf(h2.x, na.z, acc.x);  acc.y = fmaf(h2.y, na.z, acc.y);
        acc.x = fmaf(h3.x, na.w, acc.x);  acc.y = fmaf(h3.y, na.w, acc.y);
    }

    if (FUSE_POOL) {
        float v = fmaxf(acc.x + b2[lane * 2], 0.f)     * wlin[lane * 2]
                + fmaxf(acc.y + b2[lane * 2 + 1], 0.f) * wlin[lane * 2 + 1];
        #pragma unroll
        for (int m = 32; m >= 1; m >>= 1) v += __shfl_xor(v, m, 64);
        if (lane == 0) {
            int g = batch[node];
            unsafeAtomicAdd(&sums[g], v);
            unsafeAtomicAdd(&cnt[g], 1.0f);
        }
    } else {
        O[(size_t)node * 64 + lane] = pack_bf16x2(acc.x, acc.y);
    }
}

// ======================= GEMM =======================
// Y[node][f] = sum_k X'[node][k] * W[k][f]; W fp32; Y bf16.
// MODE 0: X fp32 (the raw input x). MODE 1: X bf16 + bias + relu.
// BM=64 x BN=128 x BK=32 LDS outer product; thread tile 8 nodes x 4 feats.

template<int MODE>
__global__ __launch_bounds__(256) void gemm_nodes(
    const void* __restrict__ Xv,
    const float* __restrict__ bias,
    const float* __restrict__ W,   // [128][128] row-major (k, f)
    u32* __restrict__ Y, int N)
{
    __shared__ float As[32][72];
    __shared__ float Bs[32][132];
    const int t = threadIdx.x;
    const int node0 = blockIdx.x * 64;
    const int tx = t & 31;
    const int ty = t >> 5;
    const int f0 = tx * 4;
    const int n0 = ty * 8;

    float acc[8][4];
    #pragma unroll
    for (int i = 0; i < 8; ++i)
        #pragma unroll
        for (int j = 0; j < 4; ++j) acc[i][j] = 0.f;

    const int sr  = t >> 3;
    const int sc4 = (t & 7) * 4;

    for (int k0 = 0; k0 < DIM; k0 += 32) {
        #pragma unroll
        for (int half = 0; half < 2; ++half) {
            int r = sr + half * 32;
            int node = node0 + r;
            float v[4] = {0.f, 0.f, 0.f, 0.f};
            if (node < N) {
                if (MODE == 0) {
                    const float* X = (const float*)Xv;
                    *(float4*)v = *(const float4*)&X[(size_t)node * DIM + k0 + sc4];
                } else {
                    const u32* X = (const u32*)Xv;
                    uint2 q = *(const uint2*)&X[(size_t)node * 64 + (k0 + sc4) / 2];
                    float2 ab = unpack_bf16x2(q.x);
                    float2 cd = unpack_bf16x2(q.y);
                    v[0] = ab.x; v[1] = ab.y; v[2] = cd.x; v[3] = cd.y;
                }
            }
            if (MODE == 1) {
                float bv[4];
                *(float4*)bv = *(const float4*)&bias[k0 + sc4];
                #pragma unroll
                for (int i = 0; i < 4; ++i) v[i] = fmaxf(v[i] + bv[i], 0.f);
                if (node >= N) { v[0]=v[1]=v[2]=v[3]=0.f; }
            }
            #pragma unroll
            for (int i = 0; i < 4; ++i) As[sc4 + i][r] = v[i];
        }
        #pragma unroll
        for (int i = 0; i < 4; ++i) {
            int kk = (t >> 5) + i * 8;
            float4 wv = *(const float4*)&W[(size_t)(k0 + kk) * DIM + f0];
            *(float4*)&Bs[kk][f0] = wv;
        }
        __syncthreads();

        #pragma unroll 4
        for (int kk = 0; kk < 32; ++kk) {
            float4 a0 = *(const float4*)&As[kk][n0];
            float4 a1 = *(const float4*)&As[kk][n0 + 4];
            float4 b  = *(const float4*)&Bs[kk][f0];
            float av[8] = {a0.x,a0.y,a0.z,a0.w,a1.x,a1.y,a1.z,a1.w};
            float bv[4] = {b.x,b.y,b.z,b.w};
            #pragma unroll
            for (int i = 0; i < 8; ++i)
                #pragma unroll
                for (int j = 0; j < 4; ++j)
                    acc[i][j] = fmaf(av[i], bv[j], acc[i][j]);
        }
        __syncthreads();
    }

    #pragma unroll
    for (int i = 0; i < 8; ++i) {
        int node = node0 + n0 + i;
        if (node < N) {
            uint2 o;
            o.x = pack_bf16x2(acc[i][0], acc[i][1]);
            o.y = pack_bf16x2(acc[i][2], acc[i][3]);
            *(uint2*)&Y[(size_t)node * 64 + f0 / 2] = o;
        }
    }
}

__global__ void final_kernel(const float* __restrict__ sums,
                             const float* __restrict__ cnt,
                             const float* __restrict__ blin,
                             float* __restrict__ out, int G)
{
    int g = blockIdx.x * blockDim.x + threadIdx.x;
    if (g < G) out[g] = sums[g] / fmaxf(cnt[g], 1.0f) + blin[0];
}

// ======================= launch =======================

extern "C" void kernel_launch(void* const* d_in, const int* in_sizes, int n_in,
                              void* d_out, int out_size, void* d_ws, size_t ws_size,
                              hipStream_t stream)
{
    const float* x    = (const float*)d_in[0];
    const int*   src  = (const int*)d_in[1];
    const int*   dst  = (const int*)d_in[2];
    const int*   batch= (const int*)d_in[3];
    const float* W1   = (const float*)d_in[5];
    const float* b1   = (const float*)d_in[6];
    const float* W2   = (const float*)d_in[7];
    const float* b2   = (const float*)d_in[8];
    const float* wlin = (const float*)d_in[9];
    const float* blin = (const float*)d_in[10];
    float* out = (float*)d_out;

    const int N = in_sizes[0] / DIM;
    const int E = in_sizes[1];
    const int G = out_size;
    const size_t E_pad = (size_t)E + 4 * (size_t)N;   // per-bucket pad to x4

    // layout: B0(bf16 N*64 u32), B1(bf16), dinv(N), sums(G), cnt(G),
    //         deg/cursor(N), start(N), end(N), csr_src(E_pad), csr_nrm(E_pad), total
    u32*   B0    = (u32*)d_ws;
    u32*   B1    = B0 + (size_t)N * 64;
    float* dinv  = (float*)(B1 + (size_t)N * 64);
    float* sums  = dinv + N;
    float* cnt   = sums + G;
    int*   deg_c = (int*)(cnt + G);
    int*   start = deg_c + N;
    int*   end_  = start + N;
    int*   csrs  = end_ + N;
    float* csrn  = (float*)(csrs + E_pad);
    int*   total = (int*)(csrn + E_pad);
    size_t need_bytes = ((size_t)(total + 1) - (size_t)d_ws);
    if (ws_size < need_bytes) return;   // not expected: ws has always sufficed

    const int gblocks = (N + 63) / 64;
    const int eblocks = (E + 255) / 256;

    // ---- CSR build (once, reused by both layers) ----
    hipMemsetAsync(deg_c, 0, sizeof(int) * (size_t)N, stream);
    hipMemsetAsync(total, 0, sizeof(int), stream);
    hipMemsetAsync(sums, 0, sizeof(float) * 2 * (size_t)G, stream);
    hipMemsetAsync(csrs, 0, sizeof(int) * 2 * E_pad, stream);  // zero pad slots
    edge_count<<<eblocks, 256, 0, stream>>>(deg_c, dst, E);
    alloc_offsets<<<(N + 255) / 256, 256, 0, stream>>>(deg_c, start, end_, deg_c,
                                                       dinv, total, N);
    scatter_edges<<<eblocks, 256, 0, stream>>>(src, dst, dinv, deg_c, csrs, csrn, E);

    // ---- layer 1 ----
    gemm_nodes<0><<<gblocks, 256, 0, stream>>>(x, nullptr, W1, B0, N);
    gather_agg<0><<<(N + 3) / 4, 256, 0, stream>>>(B0, B1, csrs, csrn, start, end_,
                                                   dinv, N, nullptr, nullptr,
                                                   nullptr, nullptr, nullptr);
    // ---- layer 2 (gather fused with pooling) ----
    gemm_nodes<1><<<gblocks, 256, 0, stream>>>(B1, b1, W2, B0, N);
    gather_agg<1><<<(N + 3) / 4, 256, 0, stream>>>(B0, nullptr, csrs, csrn, start,
                                                   end_, dinv, N, b2, wlin,
                                                   batch, sums, cnt);
    final_kernel<<<(G + 255) / 256, 256, 0, stream>>>(sums, cnt, blin, out, G);
}